// Round 1
// baseline (86.053 us; speedup 1.0000x reference)
//
#include <hip/hip_runtime.h>
#include <math.h>

// StridedAttention: B=1, H=16, S=2048, D=64, window=±16 (33 local), stride=32 (64 strided)
constexpr int H      = 16;
constexpr int S      = 2048;
constexpr int D      = 64;
constexpr int W      = 16;
constexpr int KSTR   = 32;
constexpr int NSTR   = S / KSTR;        // 64
constexpr int NLOC   = 2 * W + 1;       // 33
constexpr int NKEYS  = NLOC + NSTR;     // 97
constexpr int NPASS  = (NKEYS + 15) / 16; // 7
constexpr float SCALE = 0.125f;         // 1/sqrt(64)

__global__ __launch_bounds__(256) void strided_attn_kernel(
    const float* __restrict__ q,
    const float* __restrict__ k,
    const float* __restrict__ v,
    float* __restrict__ out)
{
    // per-wave softmax-prob scratch (broadcast reads in PV phase)
    __shared__ float p_lds[4][NPASS * 16];

    const int wave = threadIdx.x >> 6;
    const int lane = threadIdx.x & 63;
    const int qid  = (blockIdx.x << 2) + wave;   // 0 .. H*S-1
    const int h    = qid >> 11;                  // / 2048
    const int n    = qid & (S - 1);

    const float* __restrict__ kh   = k + (size_t)(h * S) * D;
    const float* __restrict__ vh   = v + (size_t)(h * S) * D;
    const float* __restrict__ qrow = q + (size_t)qid * D;

    // 16 groups of 4 lanes: group g handles one key per pass, lane covers 16 dims
    const int g   = lane >> 2;
    const int sub = lane & 3;

    const float4* qp = (const float4*)(qrow + sub * 16);
    const float4 q0 = qp[0], q1 = qp[1], q2 = qp[2], q3 = qp[3];

    float s[NPASS];
#pragma unroll
    for (int p = 0; p < NPASS; ++p) {
        const int jj = p * 16 + g;          // logit index 0..111
        int  pos;
        bool valid;
        if (jj < NLOC) {                    // local window key
            pos   = n - W + jj;
            valid = (pos >= 0) && (pos < S);
        } else {                            // strided key
            pos   = (jj - NLOC) * KSTR;
            valid = (jj < NKEYS) && (n > W);
        }
        const int posc = pos < 0 ? 0 : (pos > S - 1 ? S - 1 : pos);
        const float4* kp = (const float4*)(kh + (size_t)posc * D + sub * 16);
        const float4 k0 = kp[0], k1 = kp[1], k2 = kp[2], k3 = kp[3];

        float acc = q0.x * k0.x + q0.y * k0.y + q0.z * k0.z + q0.w * k0.w;
        acc      += q1.x * k1.x + q1.y * k1.y + q1.z * k1.z + q1.w * k1.w;
        acc      += q2.x * k2.x + q2.y * k2.y + q2.z * k2.z + q2.w * k2.w;
        acc      += q3.x * k3.x + q3.y * k3.y + q3.z * k3.z + q3.w * k3.w;
        // reduce the 4 dim-slices within the group
        acc += __shfl_xor(acc, 1);
        acc += __shfl_xor(acc, 2);
        s[p] = valid ? acc * SCALE : -INFINITY;
    }

    // softmax: max over 7 regs, then across the 16 groups (lane bits 2..5)
    float m = s[0];
#pragma unroll
    for (int p = 1; p < NPASS; ++p) m = fmaxf(m, s[p]);
    m = fmaxf(m, __shfl_xor(m, 4));
    m = fmaxf(m, __shfl_xor(m, 8));
    m = fmaxf(m, __shfl_xor(m, 16));
    m = fmaxf(m, __shfl_xor(m, 32));
    // m is finite: the local window always contains >=1 valid key

    float e[NPASS];
    float l = 0.f;
#pragma unroll
    for (int p = 0; p < NPASS; ++p) {
        e[p] = __expf(s[p] - m);   // exp(-inf) == 0 for masked logits
        l   += e[p];
    }
    l += __shfl_xor(l, 4);
    l += __shfl_xor(l, 8);
    l += __shfl_xor(l, 16);
    l += __shfl_xor(l, 32);
    const float inv = 1.0f / l;

    if (sub == 0) {
#pragma unroll
        for (int p = 0; p < NPASS; ++p) p_lds[wave][p * 16 + g] = e[p] * inv;
    }
    // in-wave LDS write->read ordering (no cross-wave sharing; no barrier needed)
    asm volatile("s_waitcnt lgkmcnt(0)" ::: "memory");

    // PV phase: lane = output dim; coalesced 256B/wave V-row loads
    float acc = 0.f;
#pragma unroll
    for (int j = 0; j < NLOC; ++j) {
        const int pos  = n - W + j;
        const int posc = pos < 0 ? 0 : (pos > S - 1 ? S - 1 : pos);
        acc += p_lds[wave][j] * vh[(size_t)posc * D + lane];
    }
#pragma unroll
    for (int si = 0; si < NSTR; ++si) {
        acc += p_lds[wave][NLOC + si] * vh[(size_t)(si * KSTR) * D + lane];
    }
    out[(size_t)qid * D + lane] = acc;
}

extern "C" void kernel_launch(void* const* d_in, const int* in_sizes, int n_in,
                              void* d_out, int out_size, void* d_ws, size_t ws_size,
                              hipStream_t stream) {
    const float* q = (const float*)d_in[0];
    const float* k = (const float*)d_in[1];
    const float* v = (const float*)d_in[2];
    float* out     = (float*)d_out;

    const int total_waves = H * S;          // 32768 queries, 1 wave each
    dim3 grid(total_waves / 4);             // 4 waves per block
    dim3 block(256);
    strided_attn_kernel<<<grid, block, 0, stream>>>(q, k, v, out);
}

// Round 2
// 30.663 us; speedup vs baseline: 2.8064x; 2.8064x over previous
//
#include <hip/hip_runtime.h>
#include <math.h>

// StridedAttention: B=1, H=16, S=2048, D=64, window ±16 (33 local), stride 32 (64 strided)
constexpr int H    = 16;
constexpr int S    = 2048;
constexpr int D    = 64;
constexpr int W    = 16;
constexpr int KSTR = 32;
constexpr int NSTR = 64;          // strided keys
constexpr int QB   = 64;          // queries per block
constexpr int LROWS = QB + 2 * W; // 96 local rows staged
constexpr int PAD  = 68;          // floats per LDS row (64 + 4 pad -> 2-way bank alias max)
constexpr float SCALE = 0.125f;   // 1/sqrt(64)

// phase-1 LDS layout (floats)
constexpr int OFF_Q  = 0;                     // q_s   [64][68]
constexpr int OFF_KL = OFF_Q + QB * PAD;      // k_loc [96][68]
constexpr int OFF_KS = OFF_KL + LROWS * PAD;  // k_str [64][68]
// phase-2 LDS layout (overlaps phase 1; barrier-separated)
constexpr int OFF_VL = 0;                     // v_loc [96][68]
constexpr int OFF_VS = OFF_VL + LROWS * PAD;  // v_str [64][68]
constexpr int PROW   = 116;                   // p row stride (112 entries + pad)
constexpr int OFF_P  = OFF_VS + NSTR * PAD;   // p_s [4][16][116]
constexpr int LDS_TOTAL = OFF_P + 4 * 16 * PROW;   // 18304 floats = 73216 B -> 2 blocks/CU

__global__ __launch_bounds__(256, 2) void strided_attn_kernel(
    const float* __restrict__ q,
    const float* __restrict__ k,
    const float* __restrict__ v,
    float* __restrict__ out)
{
    __shared__ float lds[LDS_TOTAL];

    const int tid  = threadIdx.x;
    const int w    = tid >> 6;        // wave 0..3, owns 16 queries
    const int lane = tid & 63;
    const int h    = blockIdx.x >> 5; // 32 blocks per head
    const int n0   = (blockIdx.x & 31) * QB;

    const float* __restrict__ qh = q + (size_t)(h * S) * D;
    const float* __restrict__ kh = k + (size_t)(h * S) * D;
    const float* __restrict__ vh = v + (size_t)(h * S) * D;

    // ---- phase 1 staging: q (1024 f4) + k_loc (1536 f4) + k_str (1024 f4) ----
    for (int t = tid; t < 3584; t += 256) {
        const float* src;
        int dst;
        if (t < 1024) {
            int r = t >> 4, d4 = t & 15;
            src = qh + (size_t)(n0 + r) * D + d4 * 4;
            dst = OFF_Q + r * PAD + d4 * 4;
        } else if (t < 2560) {
            int u = t - 1024, r = u >> 4, d4 = u & 15;
            int pos = n0 - W + r;
            pos = pos < 0 ? 0 : (pos > S - 1 ? S - 1 : pos); // clamped rows masked later
            src = kh + (size_t)pos * D + d4 * 4;
            dst = OFF_KL + r * PAD + d4 * 4;
        } else {
            int u = t - 2560, r = u >> 4, d4 = u & 15;
            src = kh + (size_t)(r * KSTR) * D + d4 * 4;
            dst = OFF_KS + r * PAD + d4 * 4;
        }
        *(float4*)&lds[dst] = *(const float4*)src;
    }
    __syncthreads();

    // ---- QK: lane = (r16, qg); 4 queries x (3 local-row slots + 4 strided keys) ----
    const int r16  = lane & 15;
    const int qg   = lane >> 4;
    const int qoff = qg * 4;          // wave-relative query base for this lane

    float acc[4][7] = {};
    const int lbase = OFF_KL + (16 * w + r16) * PAD;
    const int sbase = OFF_KS + r16 * PAD;
    const int qbase = OFF_Q + (16 * w + qoff) * PAD;

#pragma unroll 4
    for (int d4 = 0; d4 < 16; ++d4) {
        const int dd = d4 * 4;
        float4 kf[7];
        kf[0] = *(float4*)&lds[lbase + 0 * 16 * PAD + dd];
        kf[1] = *(float4*)&lds[lbase + 1 * 16 * PAD + dd];
        kf[2] = *(float4*)&lds[lbase + 2 * 16 * PAD + dd];
        kf[3] = *(float4*)&lds[sbase + 0 * 16 * PAD + dd];
        kf[4] = *(float4*)&lds[sbase + 1 * 16 * PAD + dd];
        kf[5] = *(float4*)&lds[sbase + 2 * 16 * PAD + dd];
        kf[6] = *(float4*)&lds[sbase + 3 * 16 * PAD + dd];
#pragma unroll
        for (int i = 0; i < 4; ++i) {
            float4 q4 = *(float4*)&lds[qbase + i * PAD + dd];
#pragma unroll
            for (int p = 0; p < 7; ++p) {
                acc[i][p] += q4.x * kf[p].x + q4.y * kf[p].y +
                             q4.z * kf[p].z + q4.w * kf[p].w;
            }
        }
    }

    // ---- softmax (registers + 16-lane shuffles; groups share qg = lane>>4) ----
    float pv[4][7];
#pragma unroll
    for (int i = 0; i < 4; ++i) {
        const int qo = qoff + i;                 // wave-relative query 0..15
        const int n  = n0 + 16 * w + qo;         // global position
        float s[7];
#pragma unroll
        for (int p = 0; p < 3; ++p) {
            const int rrel = r16 + 16 * p;       // wave-local staged row 0..47
            const int pos  = n0 + 16 * w + rrel - W;
            const bool ok  = (rrel >= qo) && (rrel <= qo + 2 * W) &&
                             (pos >= 0) && (pos < S);
            s[p] = ok ? acc[i][p] * SCALE : -INFINITY;
        }
        const bool us = n > W;
#pragma unroll
        for (int p = 3; p < 7; ++p) s[p] = us ? acc[i][p] * SCALE : -INFINITY;

        float m = s[0];
#pragma unroll
        for (int p = 1; p < 7; ++p) m = fmaxf(m, s[p]);
        m = fmaxf(m, __shfl_xor(m, 1));
        m = fmaxf(m, __shfl_xor(m, 2));
        m = fmaxf(m, __shfl_xor(m, 4));
        m = fmaxf(m, __shfl_xor(m, 8));

        float e[7], l = 0.f;
#pragma unroll
        for (int p = 0; p < 7; ++p) { e[p] = __expf(s[p] - m); l += e[p]; }
        l += __shfl_xor(l, 1);
        l += __shfl_xor(l, 2);
        l += __shfl_xor(l, 4);
        l += __shfl_xor(l, 8);
        const float inv = 1.0f / l;
#pragma unroll
        for (int p = 0; p < 7; ++p) pv[i][p] = e[p] * inv;
    }

    __syncthreads();   // phase-1 LDS dead; phase-2 regions may now be written

    // ---- write probabilities: p_s[w][q16][0..47 local rows | 48..111 strided] ----
#pragma unroll
    for (int i = 0; i < 4; ++i) {
        const int pb = OFF_P + (w * 16 + qoff + i) * PROW;
#pragma unroll
        for (int p = 0; p < 3; ++p) lds[pb + r16 + 16 * p] = pv[i][p];
#pragma unroll
        for (int p = 0; p < 4; ++p) lds[pb + 48 + r16 + 16 * p] = pv[i][3 + p];
    }

    // ---- stage V: v_loc (1536 f4) + v_str (1024 f4) ----
    for (int t = tid; t < 2560; t += 256) {
        const float* src;
        int dst;
        if (t < 1536) {
            int r = t >> 4, d4 = t & 15;
            int pos = n0 - W + r;
            pos = pos < 0 ? 0 : (pos > S - 1 ? S - 1 : pos);
            src = vh + (size_t)pos * D + d4 * 4;
            dst = OFF_VL + r * PAD + d4 * 4;
        } else {
            int u = t - 1536, r = u >> 4, d4 = u & 15;
            src = vh + (size_t)(r * KSTR) * D + d4 * 4;
            dst = OFF_VS + r * PAD + d4 * 4;
        }
        *(float4*)&lds[dst] = *(const float4*)src;
    }
    __syncthreads();

    // ---- PV: lane = (d16, qg); out acc 4 queries x float4 dims ----
    const int d16 = lane & 15;
    float4 o[4];
#pragma unroll
    for (int i = 0; i < 4; ++i) o[i] = make_float4(0.f, 0.f, 0.f, 0.f);

    const int pb0 = OFF_P + (w * 16 + qoff) * PROW;
    const int vlb = OFF_VL + 16 * w * PAD + d16 * 4;
    const int vsb = OFF_VS + d16 * 4;

#pragma unroll
    for (int eb = 0; eb < 12; ++eb) {            // 48 local rows
        float4 pq[4];
#pragma unroll
        for (int i = 0; i < 4; ++i)
            pq[i] = *(float4*)&lds[pb0 + i * PROW + eb * 4];
#pragma unroll
        for (int j = 0; j < 4; ++j) {
            float4 v4 = *(float4*)&lds[vlb + (eb * 4 + j) * PAD];
#pragma unroll
            for (int i = 0; i < 4; ++i) {
                const float pj = ((const float*)&pq[i])[j];
                o[i].x += pj * v4.x; o[i].y += pj * v4.y;
                o[i].z += pj * v4.z; o[i].w += pj * v4.w;
            }
        }
    }
#pragma unroll
    for (int eb = 0; eb < 16; ++eb) {            // 64 strided rows
        float4 pq[4];
#pragma unroll
        for (int i = 0; i < 4; ++i)
            pq[i] = *(float4*)&lds[pb0 + i * PROW + 48 + eb * 4];
#pragma unroll
        for (int j = 0; j < 4; ++j) {
            float4 v4 = *(float4*)&lds[vsb + (eb * 4 + j) * PAD];
#pragma unroll
            for (int i = 0; i < 4; ++i) {
                const float pj = ((const float*)&pq[i])[j];
                o[i].x += pj * v4.x; o[i].y += pj * v4.y;
                o[i].z += pj * v4.z; o[i].w += pj * v4.w;
            }
        }
    }

    // ---- store ----
#pragma unroll
    for (int i = 0; i < 4; ++i) {
        const int n = n0 + 16 * w + qoff + i;
        *(float4*)(out + ((size_t)(h * S) + n) * D + d16 * 4) = o[i];
    }
}

extern "C" void kernel_launch(void* const* d_in, const int* in_sizes, int n_in,
                              void* d_out, int out_size, void* d_ws, size_t ws_size,
                              hipStream_t stream) {
    const float* q = (const float*)d_in[0];
    const float* k = (const float*)d_in[1];
    const float* v = (const float*)d_in[2];
    float* out     = (float*)d_out;

    dim3 grid(H * (S / QB));   // 16 heads x 32 blocks = 512
    dim3 block(256);
    strided_attn_kernel<<<grid, block, 0, stream>>>(q, k, v, out);
}

// Round 3
// 18.410 us; speedup vs baseline: 4.6742x; 1.6655x over previous
//
#include <hip/hip_runtime.h>
#include <math.h>

// StridedAttention via MFMA bf16 (hi/lo split for QK accuracy)
// B=1, H=16, S=2048, D=64, window ±16 (33 local), stride 32 (64 strided)

typedef __attribute__((ext_vector_type(8))) short bf16x8;   // 8 bf16 = 4 VGPR
typedef __attribute__((ext_vector_type(4))) float f32x4;

constexpr int H = 16, S = 2048, D = 64, W = 16;
constexpr int QB      = 64;    // queries per block
constexpr int NLOCROW = 96;    // staged local rows (union of 64 windows)
constexpr int NROWS   = 160;   // 96 local + 64 strided
constexpr int NT      = 10;    // 160/16 key tiles
constexpr float SCALE = 0.125f;

// LDS layout (ushort units). Region [KHI..end) is reused for V^T + P after QK.
constexpr int QSTR = 72;                  // 64 bf16 + 8 pad (144 B rows)
constexpr int VSTR = 168;                 // 160 bf16 + 8 pad (336 B rows)
constexpr int QHI  = 0;
constexpr int QLO  = QHI + QB * QSTR;     // 4608
constexpr int KHI  = QLO + QB * QSTR;     // 9216
constexpr int KLO  = KHI + NROWS * QSTR;  // 20736
constexpr int VTB  = KHI;                 // V^T [64][168], PV phase
constexpr int PB   = VTB + D * VSTR;      // 19968, P [64][168], PV phase
constexpr int LDS_U = KLO + NROWS * QSTR; // 32256 ushort = 64512 B -> 2 blocks/CU

__device__ __forceinline__ ushort f2bf(float x) {
    union { float f; unsigned u; } t; t.f = x;
    unsigned r = t.u + 0x7fffu + ((t.u >> 16) & 1u);   // RNE
    return (ushort)(r >> 16);
}
__device__ __forceinline__ float bf2f(ushort b) {
    union { float f; unsigned u; } t; t.u = ((unsigned)b) << 16;
    return t.f;
}
__device__ __forceinline__ int rowpos(int r, int n0) {
    if (r < NLOCROW) {
        int p = n0 - W + r;                 // clamped rows are masked in softmax
        return p < 0 ? 0 : (p > S - 1 ? S - 1 : p);
    }
    return (r - NLOCROW) * 32;              // strided keys
}

__global__ __launch_bounds__(256, 2) void strided_attn_mfma(
    const float* __restrict__ q,
    const float* __restrict__ k,
    const float* __restrict__ v,
    float* __restrict__ out)
{
    __shared__ ushort lds[LDS_U];

    const int tid  = threadIdx.x;
    const int w    = tid >> 6;
    const int lane = tid & 63;
    const int h    = blockIdx.x >> 5;
    const int n0   = (blockIdx.x & 31) << 6;

    const float* __restrict__ qh = q + (size_t)(h * S) * D;
    const float* __restrict__ kh = k + (size_t)(h * S) * D;
    const float* __restrict__ vh = v + (size_t)(h * S) * D;

    // ---- V prefetch into registers (T14 issue-early / write-late) ----
    // 640 tasks: (row-pair rp 0..79) x (dim-chunk ch 0..7); 2 rows x 8 dims each.
    const int ntask = (tid < 128) ? 3 : 2;
    float4 vreg[3][4];
#pragma unroll
    for (int tt = 0; tt < 3; ++tt) {
        if (tt < ntask) {
            const int t2 = tid + (tt << 8);
            const int rp = t2 % 80, ch = t2 / 80;
            const int p0 = rowpos(2 * rp,     n0);
            const int p1 = rowpos(2 * rp + 1, n0);
            const float* s0 = vh + (size_t)p0 * D + ch * 8;
            const float* s1 = vh + (size_t)p1 * D + ch * 8;
            vreg[tt][0] = *(const float4*)s0;
            vreg[tt][1] = *(const float4*)(s0 + 4);
            vreg[tt][2] = *(const float4*)s1;
            vreg[tt][3] = *(const float4*)(s1 + 4);
        }
    }

    // ---- stage Q (hi/lo) + K (hi/lo): 1792 tasks of 8 dims, 7 iters exact ----
    for (int t = tid; t < 1792; t += 256) {
        int row, ch, dhi, dlo;
        const float* src;
        if (t < 512) {                       // Q: 64 rows x 8 chunks
            row = t >> 3; ch = t & 7;
            src = qh + (size_t)(n0 + row) * D + ch * 8;
            dhi = QHI + row * QSTR + ch * 8;
            dlo = QLO + row * QSTR + ch * 8;
        } else {                             // K union: 160 rows x 8 chunks
            const int u = t - 512;
            row = u >> 3; ch = u & 7;
            src = kh + (size_t)rowpos(row, n0) * D + ch * 8;
            dhi = KHI + row * QSTR + ch * 8;
            dlo = KLO + row * QSTR + ch * 8;
        }
        const float4 a = *(const float4*)src;
        const float4 b = *(const float4*)(src + 4);
        const float xs[8] = {a.x, a.y, a.z, a.w, b.x, b.y, b.z, b.w};
        union { bf16x8 v; ushort u[8]; } hi, lo;
#pragma unroll
        for (int j = 0; j < 8; ++j) {
            const ushort hb = f2bf(xs[j]);
            hi.u[j] = hb;
            lo.u[j] = f2bf(xs[j] - bf2f(hb));
        }
        *(bf16x8*)&lds[dhi] = hi.v;
        *(bf16x8*)&lds[dlo] = lo.v;
    }
    __syncthreads();

    // ---- QK^T: wave w computes q-band [w*16, w*16+16) x 160 keys ----
    const int band = w * 16;
    const int c = lane & 15;       // frag col/row index
    const int g = lane >> 4;       // k-group
    const int abase = (band + c) * QSTR + g * 8;
    const bf16x8 aH0 = *(bf16x8*)&lds[QHI + abase];
    const bf16x8 aH1 = *(bf16x8*)&lds[QHI + abase + 32];
    const bf16x8 aL0 = *(bf16x8*)&lds[QLO + abase];
    const bf16x8 aL1 = *(bf16x8*)&lds[QLO + abase + 32];

    f32x4 acc[NT];
#pragma unroll
    for (int t = 0; t < NT; ++t) acc[t] = (f32x4){0.f, 0.f, 0.f, 0.f};

#pragma unroll
    for (int t = 0; t < NT; ++t) {
        const int kb = (t * 16 + c) * QSTR + g * 8;
        const bf16x8 bH0 = *(bf16x8*)&lds[KHI + kb];
        const bf16x8 bH1 = *(bf16x8*)&lds[KHI + kb + 32];
        const bf16x8 bL0 = *(bf16x8*)&lds[KLO + kb];
        const bf16x8 bL1 = *(bf16x8*)&lds[KLO + kb + 32];
        f32x4 a4 = acc[t];
        a4 = __builtin_amdgcn_mfma_f32_16x16x32_bf16(aH0, bH0, a4, 0, 0, 0);
        a4 = __builtin_amdgcn_mfma_f32_16x16x32_bf16(aH1, bH1, a4, 0, 0, 0);
        a4 = __builtin_amdgcn_mfma_f32_16x16x32_bf16(aL0, bH0, a4, 0, 0, 0);
        a4 = __builtin_amdgcn_mfma_f32_16x16x32_bf16(aL1, bH1, a4, 0, 0, 0);
        a4 = __builtin_amdgcn_mfma_f32_16x16x32_bf16(aH0, bL0, a4, 0, 0, 0);
        a4 = __builtin_amdgcn_mfma_f32_16x16x32_bf16(aH1, bL1, a4, 0, 0, 0);
        acc[t] = a4;
    }

    // ---- softmax in registers; C/D: lane holds queries (g*4+i), key col c+16t ----
    float pw[4][NT];   // unnormalized exp, normalization deferred to output
    float linv[4];
#pragma unroll
    for (int i = 0; i < 4; ++i) {
        const int qi = band + g * 4 + i;     // block-relative query
        const int n  = n0 + qi;
        float s[NT];
#pragma unroll
        for (int t = 0; t < 6; ++t) {        // local slots j = 16t + c < 96
            const int j = t * 16 + c;
            const bool ok = ((unsigned)(j - qi) <= 32u) &&
                            ((unsigned)(n0 - W + j) < (unsigned)S);
            s[t] = ok ? acc[t][i] * SCALE : -INFINITY;
        }
        const bool us = n > W;
#pragma unroll
        for (int t = 6; t < NT; ++t)         // strided slots
            s[t] = us ? acc[t][i] * SCALE : -INFINITY;

        float m = s[0];
#pragma unroll
        for (int t = 1; t < NT; ++t) m = fmaxf(m, s[t]);
        m = fmaxf(m, __shfl_xor(m, 1));
        m = fmaxf(m, __shfl_xor(m, 2));
        m = fmaxf(m, __shfl_xor(m, 4));
        m = fmaxf(m, __shfl_xor(m, 8));

        float l = 0.f;
#pragma unroll
        for (int t = 0; t < NT; ++t) { pw[i][t] = __expf(s[t] - m); l += pw[i][t]; }
        l += __shfl_xor(l, 1);
        l += __shfl_xor(l, 2);
        l += __shfl_xor(l, 4);
        l += __shfl_xor(l, 8);
        linv[i] = 1.0f / l;
    }

    __syncthreads();   // all waves done reading Q/K -> region reuse is safe

    // ---- write P (bf16, [query][keyslot]) ----
#pragma unroll
    for (int i = 0; i < 4; ++i) {
        const int pb = PB + (band + g * 4 + i) * VSTR + c;
#pragma unroll
        for (int t = 0; t < NT; ++t) lds[pb + t * 16] = f2bf(pw[i][t]);
    }

    // ---- write V^T (bf16, [d][keyrow]) from prefetched registers ----
#pragma unroll
    for (int tt = 0; tt < 3; ++tt) {
        if (tt < ntask) {
            const int t2 = tid + (tt << 8);
            const int rp = t2 % 80, ch = t2 / 80;
            const float r0[8] = {vreg[tt][0].x, vreg[tt][0].y, vreg[tt][0].z, vreg[tt][0].w,
                                 vreg[tt][1].x, vreg[tt][1].y, vreg[tt][1].z, vreg[tt][1].w};
            const float r1[8] = {vreg[tt][2].x, vreg[tt][2].y, vreg[tt][2].z, vreg[tt][2].w,
                                 vreg[tt][3].x, vreg[tt][3].y, vreg[tt][3].z, vreg[tt][3].w};
#pragma unroll
            for (int j = 0; j < 8; ++j) {
                const unsigned pk = (unsigned)f2bf(r0[j]) | ((unsigned)f2bf(r1[j]) << 16);
                *(unsigned*)&lds[VTB + (ch * 8 + j) * VSTR + 2 * rp] = pk;
            }
        }
    }
    __syncthreads();

    // ---- PV: out[q][d] = P(16x160) x V(160x64), per wave band ----
    f32x4 o[4];
#pragma unroll
    for (int dt = 0; dt < 4; ++dt) o[dt] = (f32x4){0.f, 0.f, 0.f, 0.f};

#pragma unroll
    for (int kt = 0; kt < 5; ++kt) {
        const bf16x8 pa = *(bf16x8*)&lds[PB + (band + c) * VSTR + kt * 32 + g * 8];
#pragma unroll
        for (int dt = 0; dt < 4; ++dt) {
            const bf16x8 vb = *(bf16x8*)&lds[VTB + (dt * 16 + c) * VSTR + kt * 32 + g * 8];
            o[dt] = __builtin_amdgcn_mfma_f32_16x16x32_bf16(pa, vb, o[dt], 0, 0, 0);
        }
    }

    // ---- store with deferred 1/l normalization (same query<->lane map as softmax) ----
#pragma unroll
    for (int i = 0; i < 4; ++i) {
        const int n = n0 + band + g * 4 + i;
        float* op = out + ((size_t)(h * S) + n) * D + c;
#pragma unroll
        for (int dt = 0; dt < 4; ++dt) op[dt * 16] = o[dt][i] * linv[i];
    }
}

extern "C" void kernel_launch(void* const* d_in, const int* in_sizes, int n_in,
                              void* d_out, int out_size, void* d_ws, size_t ws_size,
                              hipStream_t stream) {
    (void)in_sizes; (void)n_in; (void)d_ws; (void)ws_size; (void)out_size;
    const float* q = (const float*)d_in[0];
    const float* k = (const float*)d_in[1];
    const float* v = (const float*)d_in[2];
    float* out     = (float*)d_out;

    dim3 grid(H * (S / QB));   // 512 blocks, 2 per CU
    dim3 block(256);
    strided_attn_mfma<<<grid, block, 0, stream>>>(q, k, v, out);
}

// Round 4
// 17.880 us; speedup vs baseline: 4.8129x; 1.0297x over previous
//
#include <hip/hip_runtime.h>
#include <math.h>

// StridedAttention via MFMA bf16, 2x2 wave-split (q-tile x key-half), flash-style merge
// B=1, H=16, S=2048, D=64, window ±16 (33 local), stride 32 (64 strided)

typedef __attribute__((ext_vector_type(8))) short bf16x8;   // 8 bf16 = 4 VGPR
typedef __attribute__((ext_vector_type(4))) float f32x4;

constexpr int H = 16, S = 2048, D = 64, W = 16;
constexpr int QB    = 32;     // queries per block
constexpr int NLOC  = 64;     // local union rows (QB + 2W)
constexpr int NROWS = 128;    // 64 local + 64 strided
constexpr float SCALE = 0.125f;

// LDS layout (ushort units); all row strides multiples of 8 ushort (16B) for b128.
constexpr int QSTR = 72;                 // 144 B rows
constexpr int VSTR = 136;                // 272 B rows
constexpr int QHI  = 0;                  // Q hi [32][72]
constexpr int QLO  = QHI + QB * QSTR;    // 2304: Q lo [32][72]
constexpr int KB   = QLO + QB * QSTR;    // 4608: K bf16 [128][72]
// phase-2 overlay (valid after post-QK barrier; Q/K regions dead)
constexpr int VTB  = 0;                  // V^T [64][136]
constexpr int PBF  = VTB + D * VSTR;     // 8704: P [32][136]
constexpr int MLB  = KB + NROWS * QSTR;  // 13824 (byte 27648): ml f32[32][2][2]
constexpr int LDS_U = MLB + 256;         // 14080 ushort = 28160 B -> 5 blocks/CU cap

__device__ __forceinline__ ushort f2bf(float x) {
    union { float f; unsigned u; } t; t.f = x;
    unsigned r = t.u + 0x7fffu + ((t.u >> 16) & 1u);   // RNE
    return (ushort)(r >> 16);
}
__device__ __forceinline__ float bf2f(ushort b) {
    union { float f; unsigned u; } t; t.u = ((unsigned)b) << 16;
    return t.f;
}
__device__ __forceinline__ int rowpos(int r, int n0) {
    if (r < NLOC) {
        int p = n0 - W + r;              // clamped rows masked in softmax
        return p < 0 ? 0 : (p > S - 1 ? S - 1 : p);
    }
    return (r - NLOC) * 32;              // strided keys
}

__global__ __launch_bounds__(256, 4) void strided_attn_mfma(
    const float* __restrict__ q,
    const float* __restrict__ k,
    const float* __restrict__ v,
    float* __restrict__ out)
{
    __shared__ ushort lds[LDS_U];
    float* ml = (float*)&lds[MLB];       // [q 0..31][wk][m,l]

    const int tid  = threadIdx.x;
    const int w    = tid >> 6;
    const int lane = tid & 63;
    const int wq   = w >> 1;             // q-tile 0/1 (16 queries)
    const int wk   = w & 1;              // QK: key-half; PV: d-half
    // XCD-aware bijective swizzle (1024 % 8 == 0)
    const int bid  = blockIdx.x;
    const int swz  = (bid & 7) * 128 + (bid >> 3);
    const int h    = swz >> 6;
    const int n0   = (swz & 63) << 5;

    const float* __restrict__ qh = q + (size_t)(h * S) * D;
    const float* __restrict__ kh = k + (size_t)(h * S) * D;
    const float* __restrict__ vh = v + (size_t)(h * S) * D;

    // ---- V prefetch into regs (issue-early / write-late). 512 tasks: 2 rows x 8 dims.
    float4 vreg[2][4];
#pragma unroll
    for (int tt = 0; tt < 2; ++tt) {
        const int tau = tid + (tt << 8);
        const int rp = tau & 63, ch = tau >> 6;
        const int p0 = rowpos(2 * rp,     n0);
        const int p1 = rowpos(2 * rp + 1, n0);
        const float* s0 = vh + (size_t)p0 * D + ch * 8;
        const float* s1 = vh + (size_t)p1 * D + ch * 8;
        vreg[tt][0] = *(const float4*)s0;
        vreg[tt][1] = *(const float4*)(s0 + 4);
        vreg[tt][2] = *(const float4*)s1;
        vreg[tt][3] = *(const float4*)(s1 + 4);
    }

    // ---- stage Q (hi/lo) + K (single bf16): 1280 tasks of 8 dims, 5 iters exact
    for (int t = tid; t < 1280; t += 256) {
        if (t < 256) {                   // Q: 32 rows x 8 chunks, hi+lo
            const int row = t >> 3, ch = t & 7;
            const float* src = qh + (size_t)(n0 + row) * D + ch * 8;
            const float4 a = *(const float4*)src;
            const float4 b = *(const float4*)(src + 4);
            const float xs[8] = {a.x, a.y, a.z, a.w, b.x, b.y, b.z, b.w};
            union { bf16x8 v; ushort u[8]; } hi, lo;
#pragma unroll
            for (int j = 0; j < 8; ++j) {
                const ushort hb = f2bf(xs[j]);
                hi.u[j] = hb;
                lo.u[j] = f2bf(xs[j] - bf2f(hb));
            }
            *(bf16x8*)&lds[QHI + row * QSTR + ch * 8] = hi.v;
            *(bf16x8*)&lds[QLO + row * QSTR + ch * 8] = lo.v;
        } else {                         // K: 128 rows x 8 chunks, single bf16
            const int u = t - 256;
            const int row = u >> 3, ch = u & 7;
            const float* src = kh + (size_t)rowpos(row, n0) * D + ch * 8;
            const float4 a = *(const float4*)src;
            const float4 b = *(const float4*)(src + 4);
            const float xs[8] = {a.x, a.y, a.z, a.w, b.x, b.y, b.z, b.w};
            union { bf16x8 v; ushort u[8]; } hi;
#pragma unroll
            for (int j = 0; j < 8; ++j) hi.u[j] = f2bf(xs[j]);
            *(bf16x8*)&lds[KB + row * QSTR + ch * 8] = hi.v;
        }
    }
    __syncthreads();

    // ---- QK^T: wave (wq,wk) computes 16 queries x 64 keys (wk=0 local, wk=1 strided)
    const int c = lane & 15;
    const int g = lane >> 4;
    const int abase = (wq * 16 + c) * QSTR + g * 8;
    const bf16x8 aH0 = *(bf16x8*)&lds[QHI + abase];
    const bf16x8 aH1 = *(bf16x8*)&lds[QHI + abase + 32];
    const bf16x8 aL0 = *(bf16x8*)&lds[QLO + abase];
    const bf16x8 aL1 = *(bf16x8*)&lds[QLO + abase + 32];

    f32x4 acc[4];
#pragma unroll
    for (int t = 0; t < 4; ++t) acc[t] = (f32x4){0.f, 0.f, 0.f, 0.f};
#pragma unroll
    for (int t = 0; t < 4; ++t) {
        const int kb = KB + (wk * 64 + t * 16 + c) * QSTR + g * 8;
        const bf16x8 b0 = *(bf16x8*)&lds[kb];
        const bf16x8 b1 = *(bf16x8*)&lds[kb + 32];
        f32x4 a4 = acc[t];
        a4 = __builtin_amdgcn_mfma_f32_16x16x32_bf16(aH0, b0, a4, 0, 0, 0);
        a4 = __builtin_amdgcn_mfma_f32_16x16x32_bf16(aH1, b1, a4, 0, 0, 0);
        a4 = __builtin_amdgcn_mfma_f32_16x16x32_bf16(aL0, b0, a4, 0, 0, 0);
        a4 = __builtin_amdgcn_mfma_f32_16x16x32_bf16(aL1, b1, a4, 0, 0, 0);
        acc[t] = a4;
    }

    // ---- local softmax stats; C/D: lane (c,g) holds query g*4+i, key col 16t+c
    float sv[4][4];    // logits, kept live across the merge barrier
    float mw[4], lw[4];
#pragma unroll
    for (int i = 0; i < 4; ++i) {
        const int qi = wq * 16 + g * 4 + i;      // block-relative query
        const int n  = n0 + qi;
        if (wk == 0) {
#pragma unroll
            for (int t = 0; t < 4; ++t) {
                const int j = t * 16 + c;        // local row 0..63
                const bool ok = ((unsigned)(j - qi) <= 32u) &&
                                ((unsigned)(n0 - W + j) < (unsigned)S);
                sv[i][t] = ok ? acc[t][i] * SCALE : -INFINITY;
            }
        } else {
            const bool us = n > W;
#pragma unroll
            for (int t = 0; t < 4; ++t)
                sv[i][t] = us ? acc[t][i] * SCALE : -INFINITY;
        }
        float m = fmaxf(fmaxf(sv[i][0], sv[i][1]), fmaxf(sv[i][2], sv[i][3]));
        m = fmaxf(m, __shfl_xor(m, 1));
        m = fmaxf(m, __shfl_xor(m, 2));
        m = fmaxf(m, __shfl_xor(m, 4));
        m = fmaxf(m, __shfl_xor(m, 8));
        mw[i] = m;
        const float ms = fmaxf(m, -1e30f);       // all-masked half -> exp(-inf)=0
        float l = 0.f;
#pragma unroll
        for (int t = 0; t < 4; ++t) l += __expf(sv[i][t] - ms);
        l += __shfl_xor(l, 1);
        l += __shfl_xor(l, 2);
        l += __shfl_xor(l, 4);
        l += __shfl_xor(l, 8);
        lw[i] = l;
    }
    if (c == 0) {
#pragma unroll
        for (int i = 0; i < 4; ++i) {
            const int qi = wq * 16 + g * 4 + i;
            ml[qi * 4 + wk * 2 + 0] = mw[i];
            ml[qi * 4 + wk * 2 + 1] = lw[i];
        }
    }
    __syncthreads();   // (m,l) visible; Q/K LDS regions now dead -> overlay OK

    // ---- merge stats, write P = exp(s - m_global) as bf16
    float linv[4];
#pragma unroll
    for (int i = 0; i < 4; ++i) {
        const int qi = wq * 16 + g * 4 + i;
        const float m0 = ml[qi * 4 + 0], l0 = ml[qi * 4 + 1];
        const float m1 = ml[qi * 4 + 2], l1 = ml[qi * 4 + 3];
        const float m  = fmaxf(m0, m1);          // finite: local half always valid
        const float l  = l0 * __expf(fmaxf(m0, -1e30f) - m)
                       + l1 * __expf(fmaxf(m1, -1e30f) - m);
        linv[i] = 1.0f / l;
        const int pb = PBF + qi * VSTR + wk * 64;
#pragma unroll
        for (int t = 0; t < 4; ++t)
            lds[pb + t * 16 + c] = f2bf(__expf(sv[i][t] - m));
    }

    // ---- write V^T (bf16 [d][key]) from prefetched regs
#pragma unroll
    for (int tt = 0; tt < 2; ++tt) {
        const int tau = tid + (tt << 8);
        const int rp = tau & 63, ch = tau >> 6;
        const float r0[8] = {vreg[tt][0].x, vreg[tt][0].y, vreg[tt][0].z, vreg[tt][0].w,
                             vreg[tt][1].x, vreg[tt][1].y, vreg[tt][1].z, vreg[tt][1].w};
        const float r1[8] = {vreg[tt][2].x, vreg[tt][2].y, vreg[tt][2].z, vreg[tt][2].w,
                             vreg[tt][3].x, vreg[tt][3].y, vreg[tt][3].z, vreg[tt][3].w};
#pragma unroll
        for (int j = 0; j < 8; ++j) {
            const unsigned pk = (unsigned)f2bf(r0[j]) | ((unsigned)f2bf(r1[j]) << 16);
            *(unsigned*)&lds[VTB + (ch * 8 + j) * VSTR + 2 * rp] = pk;
        }
    }
    __syncthreads();

    // ---- PV: wave (wq,wk) computes 16 queries x d-half wk*32..+31 over all 128 keys
    f32x4 o[2];
    o[0] = (f32x4){0.f, 0.f, 0.f, 0.f};
    o[1] = (f32x4){0.f, 0.f, 0.f, 0.f};
#pragma unroll
    for (int kt = 0; kt < 4; ++kt) {
        const bf16x8 pa = *(bf16x8*)&lds[PBF + (wq * 16 + c) * VSTR + kt * 32 + g * 8];
#pragma unroll
        for (int dt = 0; dt < 2; ++dt) {
            const bf16x8 vb = *(bf16x8*)&lds[VTB + (wk * 32 + dt * 16 + c) * VSTR + kt * 32 + g * 8];
            o[dt] = __builtin_amdgcn_mfma_f32_16x16x32_bf16(pa, vb, o[dt], 0, 0, 0);
        }
    }

    // ---- store with deferred 1/l (C/D: col=c=dim, row=g*4+i=query)
#pragma unroll
    for (int i = 0; i < 4; ++i) {
        const int n = n0 + wq * 16 + g * 4 + i;
        float* op = out + ((size_t)(h * S) + n) * D + wk * 32 + c;
        op[0]  = o[0][i] * linv[i];
        op[16] = o[1][i] * linv[i];
    }
}

extern "C" void kernel_launch(void* const* d_in, const int* in_sizes, int n_in,
                              void* d_out, int out_size, void* d_ws, size_t ws_size,
                              hipStream_t stream) {
    (void)in_sizes; (void)n_in; (void)d_ws; (void)ws_size; (void)out_size;
    const float* q = (const float*)d_in[0];
    const float* k = (const float*)d_in[1];
    const float* v = (const float*)d_in[2];
    float* out     = (float*)d_out;

    dim3 grid(H * (S / QB));   // 1024 blocks -> 4 resident/CU (LDS cap 5)
    dim3 block(256);
    strided_attn_mfma<<<grid, block, 0, stream>>>(q, k, v, out);
}

// Round 5
// 15.326 us; speedup vs baseline: 5.6149x; 1.1666x over previous
//
#include <hip/hip_runtime.h>
#include <math.h>

// StridedAttention, swapped-QK MFMA form: softmax in-register, P never hits LDS.
// B=1, H=16, S=2048, D=64, window ±16 (33 local), stride 32 (64 strided)

typedef __attribute__((ext_vector_type(8))) short bf16x8;   // 8 bf16 = 4 VGPR
typedef __attribute__((ext_vector_type(4))) float f32x4;

constexpr int H = 16, S = 2048, D = 64, W = 16;
constexpr int QB    = 64;     // queries per block
constexpr int NLOC  = 96;     // local union rows (QB + 2W)
constexpr int NROWS = 160;    // 96 local + 64 strided
constexpr int NT    = 10;     // key tiles of 16
constexpr float SCALE = 0.125f;

// LDS layout (ushort units); strides multiple of 8 ushort (16B) for b128.
constexpr int QSTR = 72;                  // 144 B rows
constexpr int VSTR = 168;                 // 336 B rows (160 slots + 8 pad)
constexpr int QHI  = 0;                   // Q hi [64][72]
constexpr int QLO  = QHI + QB * QSTR;     // 4608: Q lo [64][72]
constexpr int KB   = QLO + QB * QSTR;     // 9216: K bf16 [160][72]
constexpr int VTB  = 0;                   // overlay after barrier 2: V^T [64][168]
constexpr int LDS_U = KB + NROWS * QSTR;  // 20736 ushort = 41472 B -> 3 blocks/CU

__device__ __forceinline__ ushort f2bf(float x) {
    union { float f; unsigned u; } t; t.f = x;
    unsigned r = t.u + 0x7fffu + ((t.u >> 16) & 1u);   // RNE
    return (ushort)(r >> 16);
}
__device__ __forceinline__ float bf2f(ushort b) {
    union { float f; unsigned u; } t; t.u = ((unsigned)b) << 16;
    return t.f;
}
__device__ __forceinline__ unsigned pk2(float a, float b) {
    return (unsigned)f2bf(a) | ((unsigned)f2bf(b) << 16);
}
__device__ __forceinline__ int rowpos(int r, int n0) {
    if (r < NLOC) {
        int p = n0 - W + r;               // clamped rows masked in softmax
        return p < 0 ? 0 : (p > S - 1 ? S - 1 : p);
    }
    return (r - NLOC) * 32;               // strided keys
}

__global__ __launch_bounds__(256, 2) void strided_attn_mfma(
    const float* __restrict__ q,
    const float* __restrict__ k,
    const float* __restrict__ v,
    float* __restrict__ out)
{
    __shared__ ushort lds[LDS_U];

    const int tid  = threadIdx.x;
    const int w    = tid >> 6;
    const int lane = tid & 63;
    const int c    = lane & 15;
    const int g    = lane >> 4;
    // XCD-aware bijective swizzle (512 % 8 == 0): each XCD gets 2 heads
    const int bid  = blockIdx.x;
    const int swz  = (bid & 7) * 64 + (bid >> 3);
    const int h    = swz >> 5;
    const int n0   = (swz & 31) << 6;

    const float* __restrict__ qh = q + (size_t)(h * S) * D;
    const float* __restrict__ kh = k + (size_t)(h * S) * D;
    const float* __restrict__ vh = v + (size_t)(h * S) * D;

    // ---- V prefetch into regs (issue-early). 640 tasks: 2 rows x 8 dims each.
    const int ntask = (tid < 128) ? 3 : 2;
    float4 vreg[3][4];
#pragma unroll
    for (int tt = 0; tt < 3; ++tt) {
        if (tt < ntask) {
            const int tau = tid + (tt << 8);
            const int rp = tau % 80, ch = tau / 80;
            const float* s0 = vh + (size_t)rowpos(2 * rp,     n0) * D + ch * 8;
            const float* s1 = vh + (size_t)rowpos(2 * rp + 1, n0) * D + ch * 8;
            vreg[tt][0] = *(const float4*)s0;
            vreg[tt][1] = *(const float4*)(s0 + 4);
            vreg[tt][2] = *(const float4*)s1;
            vreg[tt][3] = *(const float4*)(s1 + 4);
        }
    }

    // ---- stage Q (hi/lo, 512 tasks) + K (bf16, 1280 tasks): 7 iters exact ----
    for (int t = tid; t < 1792; t += 256) {
        if (t < 512) {
            const int row = t >> 3, ch = t & 7;
            const float* src = qh + (size_t)(n0 + row) * D + ch * 8;
            const float4 a = *(const float4*)src;
            const float4 b = *(const float4*)(src + 4);
            const float xs[8] = {a.x, a.y, a.z, a.w, b.x, b.y, b.z, b.w};
            union { bf16x8 v; ushort u[8]; } hi, lo;
#pragma unroll
            for (int j = 0; j < 8; ++j) {
                const ushort hb = f2bf(xs[j]);
                hi.u[j] = hb;
                lo.u[j] = f2bf(xs[j] - bf2f(hb));
            }
            *(bf16x8*)&lds[QHI + row * QSTR + ch * 8] = hi.v;
            *(bf16x8*)&lds[QLO + row * QSTR + ch * 8] = lo.v;
        } else {
            const int u = t - 512;
            const int row = u >> 3, ch = u & 7;
            const float* src = kh + (size_t)rowpos(row, n0) * D + ch * 8;
            const float4 a = *(const float4*)src;
            const float4 b = *(const float4*)(src + 4);
            const float xs[8] = {a.x, a.y, a.z, a.w, b.x, b.y, b.z, b.w};
            union { bf16x8 v; ushort u[8]; } hi;
#pragma unroll
            for (int j = 0; j < 8; ++j) hi.u[j] = f2bf(xs[j]);
            *(bf16x8*)&lds[KB + row * QSTR + ch * 8] = hi.v;
        }
    }

    // ---- pre-pack V to bf16 pairs (hidden under barrier wait) ----
    unsigned vpk[3][8];
#pragma unroll
    for (int tt = 0; tt < 3; ++tt) {
        if (tt < ntask) {
            const float r0[8] = {vreg[tt][0].x, vreg[tt][0].y, vreg[tt][0].z, vreg[tt][0].w,
                                 vreg[tt][1].x, vreg[tt][1].y, vreg[tt][1].z, vreg[tt][1].w};
            const float r1[8] = {vreg[tt][2].x, vreg[tt][2].y, vreg[tt][2].z, vreg[tt][2].w,
                                 vreg[tt][3].x, vreg[tt][3].y, vreg[tt][3].z, vreg[tt][3].w};
#pragma unroll
            for (int j = 0; j < 8; ++j) vpk[tt][j] = pk2(r0[j], r1[j]);
        }
    }
    __syncthreads();

    // ---- QK^T swapped: S^T = K·Q^T. Wave w: 16 queries (w*16+c) x all 160 keys.
    const int qb = w * 16;
    const int qi = qb + c;               // this lane's query (block-relative)
    const int nq = n0 + qi;
    const int qa = (qb + c) * QSTR + g * 8;
    const bf16x8 bQH0 = *(bf16x8*)&lds[QHI + qa];
    const bf16x8 bQH1 = *(bf16x8*)&lds[QHI + qa + 32];
    const bf16x8 bQL0 = *(bf16x8*)&lds[QLO + qa];
    const bf16x8 bQL1 = *(bf16x8*)&lds[QLO + qa + 32];

    f32x4 acc[NT];
#pragma unroll
    for (int t = 0; t < NT; ++t) acc[t] = (f32x4){0.f, 0.f, 0.f, 0.f};
#pragma unroll
    for (int t = 0; t < NT; ++t) {
        const int kb = KB + (t * 16 + c) * QSTR + g * 8;
        const bf16x8 a0 = *(bf16x8*)&lds[kb];
        const bf16x8 a1 = *(bf16x8*)&lds[kb + 32];
        f32x4 a4 = acc[t];
        a4 = __builtin_amdgcn_mfma_f32_16x16x32_bf16(a0, bQH0, a4, 0, 0, 0);
        a4 = __builtin_amdgcn_mfma_f32_16x16x32_bf16(a1, bQH1, a4, 0, 0, 0);
        a4 = __builtin_amdgcn_mfma_f32_16x16x32_bf16(a0, bQL0, a4, 0, 0, 0);
        a4 = __builtin_amdgcn_mfma_f32_16x16x32_bf16(a1, bQL1, a4, 0, 0, 0);
        acc[t] = a4;
    }

    // ---- softmax fully in-lane: lane holds keys {16t+4g+i} for query qi ----
    float p[NT][4];
#pragma unroll
    for (int t = 0; t < 6; ++t) {        // local tiles: rows j = 16t+4g+i (0..95)
#pragma unroll
        for (int i = 0; i < 4; ++i) {
            const int j = t * 16 + 4 * g + i;
            const bool ok = ((unsigned)(j - qi) <= 32u) &&
                            ((unsigned)(n0 - W + j) < (unsigned)S);
            p[t][i] = ok ? acc[t][i] * SCALE : -INFINITY;
        }
    }
    const bool us = nq > W;
#pragma unroll
    for (int t = 6; t < NT; ++t)
#pragma unroll
        for (int i = 0; i < 4; ++i)
            p[t][i] = us ? acc[t][i] * SCALE : -INFINITY;

    float m = -INFINITY;
#pragma unroll
    for (int t = 0; t < NT; ++t)
#pragma unroll
        for (int i = 0; i < 4; ++i) m = fmaxf(m, p[t][i]);
    m = fmaxf(m, __shfl_xor(m, 16));
    m = fmaxf(m, __shfl_xor(m, 32));     // finite: self-key always valid

    float l = 0.f;
#pragma unroll
    for (int t = 0; t < NT; ++t)
#pragma unroll
        for (int i = 0; i < 4; ++i) { p[t][i] = __expf(p[t][i] - m); l += p[t][i]; }
    l += __shfl_xor(l, 16);
    l += __shfl_xor(l, 32);
    const float inv = 1.0f / l;

    // ---- pack P into PV A-frags in-register (k-permutation shared with V^T) ----
    union { bf16x8 v; unsigned u[4]; } pa[5];
#pragma unroll
    for (int kt = 0; kt < 5; ++kt) {
        pa[kt].u[0] = pk2(p[2 * kt][0] * inv,     p[2 * kt][1] * inv);
        pa[kt].u[1] = pk2(p[2 * kt][2] * inv,     p[2 * kt][3] * inv);
        pa[kt].u[2] = pk2(p[2 * kt + 1][0] * inv, p[2 * kt + 1][1] * inv);
        pa[kt].u[3] = pk2(p[2 * kt + 1][2] * inv, p[2 * kt + 1][3] * inv);
    }

    __syncthreads();   // all waves done with Q/K LDS -> V^T overlay safe

    // ---- write V^T at permuted slots: key 32kt+16u+4g2+j -> slot 32kt+8g2+4u+j
#pragma unroll
    for (int tt = 0; tt < 3; ++tt) {
        if (tt < ntask) {
            const int tau = tid + (tt << 8);
            const int rp = tau % 80, ch = tau / 80;
            const int kk = 2 * rp;
            const int kt = kk >> 5, rem = kk & 31;
            const int slot = kt * 32 + ((rem >> 2) & 3) * 8 + (rem >> 4) * 4 + (rem & 3);
#pragma unroll
            for (int j = 0; j < 8; ++j)
                *(unsigned*)&lds[VTB + (ch * 8 + j) * VSTR + slot] = vpk[tt][j];
        }
    }
    __syncthreads();

    // ---- PV: o[q][d] = P(16x160) x V(160x64); A = pa (in-reg), B = V^T ----
    f32x4 o[4];
#pragma unroll
    for (int dt = 0; dt < 4; ++dt) o[dt] = (f32x4){0.f, 0.f, 0.f, 0.f};
#pragma unroll
    for (int kt = 0; kt < 5; ++kt) {
#pragma unroll
        for (int dt = 0; dt < 4; ++dt) {
            const bf16x8 vb = *(bf16x8*)&lds[VTB + (dt * 16 + c) * VSTR + kt * 32 + g * 8];
            o[dt] = __builtin_amdgcn_mfma_f32_16x16x32_bf16(pa[kt].v, vb, o[dt], 0, 0, 0);
        }
    }

    // ---- store (D row = query qb+4g+i, col c = dim within tile; P pre-normalized)
#pragma unroll
    for (int i = 0; i < 4; ++i) {
        const int n = n0 + qb + 4 * g + i;
        float* op = out + ((size_t)(h * S) + n) * D + c;
#pragma unroll
        for (int dt = 0; dt < 4; ++dt) op[dt * 16] = o[dt][i];
    }
}

extern "C" void kernel_launch(void* const* d_in, const int* in_sizes, int n_in,
                              void* d_out, int out_size, void* d_ws, size_t ws_size,
                              hipStream_t stream) {
    (void)in_sizes; (void)n_in; (void)d_ws; (void)ws_size; (void)out_size;
    const float* q = (const float*)d_in[0];
    const float* k = (const float*)d_in[1];
    const float* v = (const float*)d_in[2];
    float* out     = (float*)d_out;

    dim3 grid(H * (S / QB));   // 512 blocks
    dim3 block(256);
    strided_attn_mfma<<<grid, block, 0, stream>>>(q, k, v, out);
}